// Round 1
// 270.891 us; speedup vs baseline: 1.0958x; 1.0958x over previous
//
#include <hip/hip_runtime.h>
#include <hip/hip_bf16.h>

#define D_HID 32
#define D_IN 128
#define NEG 0.2f
#define BSH 7          // log2 bucket size
#define BSZ 128        // dst nodes per bucket
#define MAXB 1024      // max buckets (N <= 131072)

typedef unsigned short u16;
typedef __attribute__((ext_vector_type(8))) short short8;   // 8 bf16 (4 VGPRs)
typedef __attribute__((ext_vector_type(4))) float float4v;  // 4 fp32 acc

__device__ __forceinline__ float b2f(u16 u){
  union { unsigned int i; float f; } c; c.i = ((unsigned int)u) << 16; return c.f;
}

__device__ __forceinline__ u16 f2b_rne(float f){
  union { float f; unsigned int u; } c; c.f = f;
  unsigned int u = c.u;
  return (u16)((u + 0x7FFFu + ((u >> 16) & 1u)) >> 16);
}

// fp32 -> bf16 hi + bf16 lo (captures ~16 mantissa bits)
__device__ __forceinline__ void split_bf16(float v, u16& hi, u16& lo){
  hi = f2b_rne(v);
  lo = f2b_rne(v - b2f(hi));
}

__device__ __forceinline__ float ldf(const void* __restrict__ p, int f32, long long i){
  return f32 ? ((const float*)p)[i] : b2f(((const u16*)p)[i]);
}

__device__ __forceinline__ int atomAddI(int* p, int v){
  return __hip_atomic_fetch_add(p, v, __ATOMIC_RELAXED, __HIP_MEMORY_SCOPE_AGENT);
}

// flags[0]: edge_index is int64-layout. flags[1]: float inputs are fp32.
__global__ void detect_flags(const int* __restrict__ ei, const u16* __restrict__ xw,
                             int* __restrict__ flags){
  __shared__ int insane_s, nz_s;
  int t = threadIdx.x;
  if (t == 0){ insane_s = 0; nz_s = 0; }
  __syncthreads();
  int pred = (t < 64) ? (ei[2*t+1] != 0) : 0;
  int e = (xw[t] >> 7) & 0xFF;
  int bad = (e < 100 || e > 140) ? 1 : 0;
  #pragma unroll
  for (int off = 32; off >= 1; off >>= 1){
    bad  += __shfl_down(bad,  off, 64);
    pred += __shfl_down(pred, off, 64);
  }
  if ((t & 63) == 0){
    atomicAdd(&insane_s, bad);
    atomicAdd(&nz_s, pred);
  }
  __syncthreads();
  if (t == 0){
    flags[0] = (nz_s == 0) ? 1 : 0;
    flags[1] = (insane_s > 16) ? 1 : 0;
  }
}

__device__ __forceinline__ void edge_nodes(const int* __restrict__ ei, int E_, int is64,
                                           int e, int& src, int& dst){
  if (is64){ src = ei[2*e]; dst = ei[2*E_ + 2*e]; }
  else     { src = ei[e];   dst = ei[E_ + e]; }
}

// ---------------- W-fragment precompute (verified r11) ----------------
__global__ void prep_wfrag(const void* __restrict__ Wl, const void* __restrict__ Wr,
                           const int* __restrict__ flags, int K,
                           uint4* __restrict__ whi, uint4* __restrict__ wlo){
  int t = blockIdx.x * blockDim.x + threadIdx.x;
  int KS = K >> 5;
  int total = 4 * KS * 64;
  if (t >= total) return;
  int lane = t & 63;
  int rem = t >> 6;            // ctile*KS + kstep
  int kstep = rem % KS;
  int ctile = rem / KS;
  int f32 = flags[1];
  int col = ctile * 16 + (lane & 15);
  int quad = lane >> 4;
  union { u16 s[8]; uint4 q; } ch, cl;
  #pragma unroll
  for (int j = 0; j < 8; ++j){
    int k = kstep*32 + quad*8 + j;
    float v = (col < 32) ? ldf(Wl, f32, (long long)k*D_HID + col)
                         : ldf(Wr, f32, (long long)k*D_HID + (col - 32));
    u16 hi, lo; split_bf16(v, hi, lo);
    ch.s[j] = hi; cl.s[j] = lo;
  }
  whi[rem*64 + lane] = ch.q;
  wlo[rem*64 + lane] = cl.q;
}

// ---------------- MFMA node transform (split-bf16, verified r11) -----------------
template<int K>
__global__ void mfma_gemm(const void* __restrict__ X,
                          const uint4* __restrict__ whi, const uint4* __restrict__ wlo,
                          const int* __restrict__ flags, int force_f32,
                          float* __restrict__ xl, float* __restrict__ xr, int N_)
{
  constexpr int KS = K >> 5;
  int tile = blockIdx.x * (blockDim.x >> 6) + (threadIdx.x >> 6);
  if (tile * 16 >= N_) return;
  int lane = threadIdx.x & 63;
  int quad = lane >> 4;
  int m = tile*16 + (lane & 15);
  if (m >= N_) m = N_ - 1;             // tail-safe loads (stores guarded)
  int f32 = force_f32 | flags[1];

  float4v acc[4];
  #pragma unroll
  for (int c = 0; c < 4; ++c) acc[c] = (float4v){0.f,0.f,0.f,0.f};

  #pragma unroll
  for (int ks = 0; ks < KS; ++ks){
    long long base = (long long)m * K + ks*32 + quad*8;
    float av[8];
    if (f32){
      const float4* xp = (const float4*)((const float*)X + base);
      float4 t0 = xp[0], t1 = xp[1];
      av[0]=t0.x; av[1]=t0.y; av[2]=t0.z; av[3]=t0.w;
      av[4]=t1.x; av[5]=t1.y; av[6]=t1.z; av[7]=t1.w;
    } else {
      union { uint4 q; u16 s[8]; } c8;
      c8.q = *(const uint4*)((const u16*)X + base);
      #pragma unroll
      for (int j = 0; j < 8; ++j) av[j] = b2f(c8.s[j]);
    }
    short8 ahi, alo;
    #pragma unroll
    for (int j = 0; j < 8; ++j){
      u16 hi, lo; split_bf16(av[j], hi, lo);
      ahi[j] = (short)hi; alo[j] = (short)lo;
    }
    #pragma unroll
    for (int c = 0; c < 4; ++c){
      uint4 wh = whi[(c*KS + ks)*64 + lane];
      uint4 wl = wlo[(c*KS + ks)*64 + lane];
      short8 bh = *(short8*)&wh;
      short8 bl = *(short8*)&wl;
      acc[c] = __builtin_amdgcn_mfma_f32_16x16x32_bf16(ahi, bh, acc[c], 0, 0, 0);
      acc[c] = __builtin_amdgcn_mfma_f32_16x16x32_bf16(ahi, bl, acc[c], 0, 0, 0);
      acc[c] = __builtin_amdgcn_mfma_f32_16x16x32_bf16(alo, bh, acc[c], 0, 0, 0);
    }
  }

  #pragma unroll
  for (int c = 0; c < 4; ++c){
    int col = c*16 + (lane & 15);
    float* dst = (col < 32) ? xl : xr;
    int kk = col & 31;
    #pragma unroll
    for (int r = 0; r < 4; ++r){
      int node = tile*16 + quad*4 + r;
      if (node < N_) dst[(size_t)node*D_HID + kk] = acc[c][r];
    }
  }
}

// ---------------- bucket count (LDS histogram, verified r8) ----------------
__global__ void bucket_count(const int* __restrict__ ei, const int* __restrict__ flags,
                             int* __restrict__ gcnt, int E_, int B_){
  __shared__ int hist[MAXB];
  for (int i = threadIdx.x; i < B_; i += 256) hist[i] = 0;
  __syncthreads();
  int chunk = (E_ + gridDim.x - 1) / gridDim.x;
  int s = blockIdx.x * chunk;
  int e = s + chunk; if (e > E_) e = E_;
  int is64 = flags[0];
  for (int i = s + (int)threadIdx.x; i < e; i += 256){
    int dst = is64 ? ei[2*E_ + 2*i] : ei[E_ + i];
    atomicAdd(&hist[dst >> BSH], 1);
  }
  __syncthreads();
  for (int i = threadIdx.x; i < B_; i += 256)
    if (hist[i]) (void)atomAddI(&gcnt[i], hist[i]);
}

// ---------------- exclusive scan over bucket counts (verified r8) ----------------
__global__ void scan_buckets(const int* __restrict__ gcnt, int* __restrict__ offsets,
                             int* __restrict__ cursor, int B_){
  __shared__ int sd[1024];
  int t = threadIdx.x;
  int v = (t < B_) ? gcnt[t] : 0;
  sd[t] = v;
  __syncthreads();
  for (int off = 1; off < 1024; off <<= 1){
    int tmp = (t >= off) ? sd[t-off] : 0;
    __syncthreads();
    sd[t] += tmp;
    __syncthreads();
  }
  if (t < B_){
    int excl = sd[t] - v;
    offsets[t] = excl;
    cursor[t]  = excl;
    if (t == B_-1) offsets[B_] = sd[t];
  }
}

// ---------------- bucket scatter with per-block range reservation (verified r8) ---
__global__ void bucket_scatter(const int* __restrict__ ei, const int* __restrict__ flags,
                               int* __restrict__ cursor, unsigned* __restrict__ seg,
                               int E_, int B_){
  __shared__ int hist[MAXB];
  __shared__ int bbase[MAXB];
  for (int i = threadIdx.x; i < B_; i += 256) hist[i] = 0;
  __syncthreads();
  int chunk = (E_ + gridDim.x - 1) / gridDim.x;
  int s = blockIdx.x * chunk;
  int e = s + chunk; if (e > E_) e = E_;
  int is64 = flags[0];
  for (int i = s + (int)threadIdx.x; i < e; i += 256){
    int dst = is64 ? ei[2*E_ + 2*i] : ei[E_ + i];
    atomicAdd(&hist[dst >> BSH], 1);
  }
  __syncthreads();
  for (int i = threadIdx.x; i < B_; i += 256){
    int c = hist[i];
    bbase[i] = c ? atomAddI(&cursor[i], c) : 0;
  }
  __syncthreads();
  for (int i = threadIdx.x; i < B_; i += 256) hist[i] = 0;  // reuse as local offset
  __syncthreads();
  for (int i = s + (int)threadIdx.x; i < e; i += 256){
    int src, dst;
    edge_nodes(ei, E_, is64, i, src, dst);
    int b = dst >> BSH;
    int pos = bbase[b] + atomicAdd(&hist[b], 1);
    seg[pos] = ((unsigned)src << BSH) | (unsigned)(dst & (BSZ-1));
  }
}

// ---------------- bucket finalize: exact per-dst CSR (verified r9) ----------------
// NOTE: csr now stores the PACKED edge word (src<<7 | dst_local). The gather
// derives the src byte offset as (en & ~127u) == src*128 (D_HID*4 == 128 bytes),
// killing the per-lane v_mul in the hot loop.
__global__ void bucket_finalize(const unsigned* __restrict__ seg,
                                const int* __restrict__ offsets,
                                int* __restrict__ row, int* __restrict__ csr_src,
                                int N_, int B_){
  __shared__ int hist[BSZ];
  __shared__ int sc[BSZ];
  __shared__ int loff[BSZ];
  int b = blockIdx.x;
  int t = threadIdx.x;
  int base = offsets[b], cnt = offsets[b+1] - base;
  if (t < BSZ) hist[t] = 0;
  __syncthreads();
  for (int i = t; i < cnt; i += 256)
    atomicAdd(&hist[seg[base+i] & (BSZ-1)], 1);
  __syncthreads();
  if (t < BSZ) sc[t] = hist[t];
  __syncthreads();
  for (int off = 1; off < BSZ; off <<= 1){
    int tmp = (t < BSZ && t >= off) ? sc[t-off] : 0;
    __syncthreads();
    if (t < BSZ) sc[t] += tmp;
    __syncthreads();
  }
  if (t < BSZ){
    int excl = sc[t] - hist[t];
    loff[t] = excl;
    int node = b*BSZ + t;
    if (node <= N_) row[node] = base + excl;
  }
  if (b == B_-1 && t == 0) row[N_] = offsets[B_];
  __syncthreads();
  for (int i = t; i < cnt; i += 256){
    unsigned en = seg[base+i];
    int dl = en & (BSZ-1);
    int pos = atomicAdd(&loff[dl], 1);
    csr_src[base + pos] = (int)en;          // packed: (src<<7)|dl
  }
}

// ---------------- group-per-node gather: 8 lanes per dst node ----------------
// Wave = 8 independent dst nodes (one per 8-lane group). Each group iterates its
// node's CSR edges one at a time with a 2-stage pipeline (csr word 2-ahead, xl
// gather 1-ahead). No cross-group combine: the width-8 dot reduce leaves the
// full logit in every lane, so softmax sum and the weighted feature accumulation
// are group-local. Prologue/epilogue (xrk load, att, bias, divide, store) are
// the same wave-insts for all 8 nodes -> 8x amortized vs wave-per-node.
// xr/row/out accesses are coalesced across the 8 consecutive nodes of a wave.
__global__ void gat_gather(const int* __restrict__ row, const unsigned* __restrict__ csrp,
                           const float* __restrict__ xl, const float* __restrict__ xr,
                           const void* __restrict__ att, const void* __restrict__ bias,
                           const int* __restrict__ flags,
                           float* __restrict__ outp, int N_, int do_relu)
{
  int G = (blockIdx.x * blockDim.x + threadIdx.x) >> 3;   // one node per 8-lane group
  if (G >= N_) return;
  int fl = threadIdx.x & 7;                               // feature block 0..7
  int f32 = flags[1];
  float4 attk;
  attk.x = ldf(att, f32, fl*4+0);
  attk.y = ldf(att, f32, fl*4+1);
  attk.z = ldf(att, f32, fl*4+2);
  attk.w = ldf(att, f32, fl*4+3);
  int n = G;
  float4 xrk = *(const float4*)(xr + (size_t)n*D_HID + fl*4);
  int rs = row[n], re = row[n+1];
  const char* xlb = (const char*)xl;
  unsigned fo = (unsigned)(fl << 4);

  // 2-stage pipeline: enB holds csr word 1 edge ahead; xlA holds gather for
  // the current edge; next gather issues before current compute.
  unsigned enB = 0;
  float4 xlA = make_float4(0.f, 0.f, 0.f, 0.f);
  if (rs < re){
    unsigned enA = csrp[rs];
    if (rs + 1 < re) enB = csrp[rs+1];
    xlA = *(const float4*)(xlb + (enA & ~127u) + fo);
  }

  float4 acc = make_float4(0.f, 0.f, 0.f, 0.f);
  float ssum = 0.f;
  for (int i = rs; i < re; ++i){
    float4 xv = xlA;
    unsigned enN = enB;
    if (i + 2 < re) enB = csrp[i+2];                       // csr 2-ahead
    if (i + 1 < re) xlA = *(const float4*)(xlb + (enN & ~127u) + fo);  // xl 1-ahead
    float4 hh;
    hh.x = xv.x + xrk.x; hh.x = fmaxf(hh.x, NEG*hh.x);
    hh.y = xv.y + xrk.y; hh.y = fmaxf(hh.y, NEG*hh.y);
    hh.z = xv.z + xrk.z; hh.z = fmaxf(hh.z, NEG*hh.z);
    hh.w = xv.w + xrk.w; hh.w = fmaxf(hh.w, NEG*hh.w);
    float p = hh.x*attk.x;
    p = fmaf(hh.y, attk.y, p);
    p = fmaf(hh.z, attk.z, p);
    p = fmaf(hh.w, attk.w, p);
    p += __shfl_xor(p, 1, 8);
    p += __shfl_xor(p, 2, 8);
    p += __shfl_xor(p, 4, 8);
    p = fminf(p, 60.f);                                   // safety clamp
    float ev = __expf(p);
    ssum += ev;
    acc.x = fmaf(ev, xv.x, acc.x);
    acc.y = fmaf(ev, xv.y, acc.y);
    acc.z = fmaf(ev, xv.z, acc.z);
    acc.w = fmaf(ev, xv.w, acc.w);
  }

  float inv = 1.0f / (ssum + 1e-16f);
  float4 o;
  o.x = acc.x*inv + ldf(bias, f32, fl*4+0);
  o.y = acc.y*inv + ldf(bias, f32, fl*4+1);
  o.z = acc.z*inv + ldf(bias, f32, fl*4+2);
  o.w = acc.w*inv + ldf(bias, f32, fl*4+3);
  if (do_relu){
    o.x = fmaxf(o.x, 0.f); o.y = fmaxf(o.y, 0.f);
    o.z = fmaxf(o.z, 0.f); o.w = fmaxf(o.w, 0.f);
  }
  *(float4*)(outp + (size_t)n*D_HID + fl*4) = o;
}

extern "C" void kernel_launch(void* const* d_in, const int* in_sizes, int n_in,
                              void* d_out, int out_size, void* d_ws, size_t ws_size,
                              hipStream_t stream)
{
  const void* x   = d_in[0];
  const int*  ei  = (const int*)d_in[1];
  const void* W1l = d_in[2];
  const void* W1r = d_in[3];
  const void* att1= d_in[4];
  const void* b1  = d_in[5];
  const void* W2l = d_in[6];
  const void* W2r = d_in[7];
  const void* att2= d_in[8];
  const void* b2  = d_in[9];
  float* out = (float*)d_out;

  int N_ = in_sizes[0] / D_IN;
  int E_ = in_sizes[1] / 2;
  int B_ = (N_ + BSZ - 1) / BSZ;

  char* ws = (char*)d_ws;
  size_t off = 0;
  auto carve = [&](size_t bytes) -> char* {
    char* p = ws + off;
    off += (bytes + 255) & ~(size_t)255;
    return p;
  };
  float*    xl      = (float*)   carve((size_t)N_ * D_HID * 4);
  float*    xr      = (float*)   carve((size_t)N_ * D_HID * 4);
  float*    h       = (float*)   carve((size_t)N_ * D_HID * 4);
  unsigned* seg     = (unsigned*)carve((size_t)E_ * 4);
  int*      csr_src = (int*)     carve((size_t)E_ * 4);
  int*      row     = (int*)     carve((size_t)(N_ + 1) * 4);
  int*      offsets = (int*)     carve((size_t)(MAXB + 1) * 4);
  int*      gcnt    = (int*)     carve((size_t)MAXB * 4);
  int*      cursor  = (int*)     carve((size_t)MAXB * 4);
  int*      flags   = (int*)     carve(256);
  uint4*    whi1    = (uint4*)   carve((size_t)4 * 4 * 64 * 16);  // K=128
  uint4*    wlo1    = (uint4*)   carve((size_t)4 * 4 * 64 * 16);
  uint4*    whi2    = (uint4*)   carve((size_t)4 * 1 * 64 * 16);  // K=32
  uint4*    wlo2    = (uint4*)   carve((size_t)4 * 1 * 64 * 16);

  const int tpb = 256;
  int gG = (N_ + 31) / 32;                  // group-per-node grid (32 nodes/block)
  int tiles = (N_ + 15) / 16;
  int gT = (tiles + 3) / 4;                 // mfma grid (4 waves/block)

  detect_flags<<<1, 256, 0, stream>>>(ei, (const u16*)x, flags);

  // ---- W fragments ----
  prep_wfrag<<<4, 256, 0, stream>>>(W1l, W1r, flags, D_IN, whi1, wlo1);
  prep_wfrag<<<1, 256, 0, stream>>>(W2l, W2r, flags, D_HID, whi2, wlo2);

  // ---- CSR build (shared by both layers) ----
  hipMemsetAsync(gcnt, 0, (size_t)MAXB * 4, stream);
  bucket_count<<<256, tpb, 0, stream>>>(ei, flags, gcnt, E_, B_);
  scan_buckets<<<1, 1024, 0, stream>>>(gcnt, offsets, cursor, B_);
  bucket_scatter<<<256, tpb, 0, stream>>>(ei, flags, cursor, seg, E_, B_);
  bucket_finalize<<<B_, tpb, 0, stream>>>(seg, offsets, row, csr_src, N_, B_);

  // ---- layer 1 ----
  mfma_gemm<D_IN><<<gT, tpb, 0, stream>>>(x, whi1, wlo1, flags, 0, xl, xr, N_);
  gat_gather<<<gG, tpb, 0, stream>>>(row, (const unsigned*)csr_src, xl, xr,
                                     att1, b1, flags, h, N_, 1);

  // ---- layer 2 ----
  mfma_gemm<D_HID><<<gT, tpb, 0, stream>>>(h, whi2, wlo2, flags, 1, xl, xr, N_);
  gat_gather<<<gG, tpb, 0, stream>>>(row, (const unsigned*)csr_src, xl, xr,
                                     att2, b2, flags, out, N_, 0);
}